// Round 4
// baseline (340.279 us; speedup 1.0000x reference)
//
#include <hip/hip_runtime.h>
#include <hip/hip_bf16.h>

#define N_SEND 12288
#define N_REC  49152
#define NEDGE  196608
#define ECAP   512

typedef __attribute__((ext_vector_type(8)))  short short8;
typedef __attribute__((ext_vector_type(4)))  short shortx4;
typedef __attribute__((ext_vector_type(4)))  float floatx4;
typedef __attribute__((ext_vector_type(16))) float floatx16;
typedef __attribute__((ext_vector_type(4)))  unsigned int uintx4;

__device__ inline short f2bs(float f) {
    __hip_bfloat16 h = __float2bfloat16(f);
    return *reinterpret_cast<short*>(&h);
}
// jax.nn.gelu default approximate=True (tanh form)
__device__ inline float gelu_tanh(float x) {
    const float k0 = 0.7978845608028654f;
    float u = k0 * (x + 0.044715f * x * x * x);
    float e = __expf(2.0f * u);
    float t = 1.0f - 2.0f / (e + 1.0f);
    return 0.5f * x * (1.0f + t);
}

// ---- prep: BT1[n][0:256]=Wl1lo^T, BT1[n][256:512]=(We2@Wl1hi)^T, WT2=Wl2^T, cvec=be2@Wl1hi
__global__ void prep_kernel(const float* __restrict__ We2, const float* __restrict__ be2,
                            const float* __restrict__ Wl1, const float* __restrict__ Wl2,
                            short* __restrict__ BT1, short* __restrict__ WT2,
                            float* __restrict__ cvec) {
    int i = blockIdx.x;
    int n = threadIdx.x;
    if (i < 256) {
        float acc = 0.f;
        for (int j = 0; j < 256; ++j)
            acc += We2[i * 256 + j] * Wl1[(256 + j) * 256 + n];
        BT1[n * 512 + i]       = f2bs(Wl1[i * 256 + n]);   // k<256: Wl1lo
        BT1[n * 512 + 256 + i] = f2bs(acc);                // k>=256: M = We2@Wl1hi
        WT2[n * 256 + i]       = f2bs(Wl2[i * 256 + n]);
    } else {
        float acc = 0.f;
        for (int j = 0; j < 256; ++j)
            acc += be2[j] * Wl1[(256 + j) * 256 + n];
        cvec[n] = acc;
    }
}

// ---- xcast: Xb = bf16(X), [2][N_SEND][256]
__global__ void xcast_kernel(const float* __restrict__ X, short* __restrict__ Xb) {
    int i = (blockIdx.x * 256 + threadIdx.x) * 8;
    floatx4 v0 = *(const floatx4*)(X + i);
    floatx4 v1 = *(const floatx4*)(X + i + 4);
    short8 p;
#pragma unroll
    for (int j = 0; j < 4; ++j) { p[j] = f2bs(v0[j]); p[j + 4] = f2bs(v1[j]); }
    *(short8*)(Xb + i) = p;
}

// ---- bounds: bnd[r] = lower_bound(idx_rec, r), r in [0, N_REC]
__global__ void bounds_kernel(const int* __restrict__ idx_rec, int* __restrict__ bnd) {
    int r = blockIdx.x * 256 + threadIdx.x;
    if (r > N_REC) return;
    int lo = 0, hi = NEDGE;
    while (lo < hi) { int mid = (lo + hi) >> 1; if (idx_rec[mid] < r) lo = mid + 1; else hi = mid; }
    bnd[r] = lo;
}

// ---- aggregate: Xagg[b][r][:] = sum_e bf16X[b][send(e)][:]; Hagg[r][:] = sum_e gelu(ea@We1+be1)
// Block owns 32 receivers. Edge idx+attr staged in LDS (coalesced). Thread = (8-col group cg,
// batch b, receiver-quarter rq): one b128 Xb load per edge; gelu split across the two b halves.
__global__ __launch_bounds__(256)
void aggregate(const int* __restrict__ idx_send, const int* __restrict__ bnd,
               const float* __restrict__ EA, const float* __restrict__ We1,
               const float* __restrict__ be1, const short* __restrict__ Xb,
               short* __restrict__ Xagg, short* __restrict__ Hagg) {
    __shared__ int sb[33];
    __shared__ int s_idx[ECAP];
    __shared__ float s_ea[ECAP * 4];
    int t = threadIdx.x;
    int r0 = blockIdx.x * 32;
    if (t < 33) sb[t] = bnd[r0 + t];
    __syncthreads();
    int e0 = sb[0], eN = sb[32];

    int cg = t & 31;
    int b  = (t >> 5) & 1;
    int rq = t >> 6;
    int c8 = cg * 8;
    int hc = c8 + 4 * b;

    floatx4 w0 = *(const floatx4*)(We1 + hc);
    floatx4 w1 = *(const floatx4*)(We1 + 256 + hc);
    floatx4 w2 = *(const floatx4*)(We1 + 512 + hc);
    floatx4 w3 = *(const floatx4*)(We1 + 768 + hc);
    floatx4 bb = *(const floatx4*)(be1 + hc);

    const short* xb_t = Xb + (size_t)b * N_SEND * 256 + c8;

    float xacc[8][8];
    float hacc[8][4];
#pragma unroll
    for (int r = 0; r < 8; ++r) {
#pragma unroll
        for (int c = 0; c < 8; ++c) xacc[r][c] = 0.f;
#pragma unroll
        for (int c = 0; c < 4; ++c) hacc[r][c] = 0.f;
    }

    for (int base = e0; base < eN; base += ECAP) {
        int cnt = min(ECAP, eN - base);
        __syncthreads();
        for (int i = t; i < cnt; i += 256) {
            s_idx[i] = idx_send[base + i];
            *(floatx4*)(s_ea + 4 * i) = *(const floatx4*)(EA + (size_t)(base + i) * 4);
        }
        __syncthreads();
#pragma unroll
        for (int r = 0; r < 8; ++r) {
            int rr = rq * 8 + r;
            int es = max(sb[rr], base);
            int ee = min(sb[rr + 1], base + cnt);
            for (int e = es; e < ee; ++e) {
                int li = e - base;
                int s = s_idx[li];
                uintx4 xv = *(const uintx4*)(xb_t + (size_t)s * 256);
                floatx4 a = *(const floatx4*)(s_ea + 4 * li);
#pragma unroll
                for (int dw = 0; dw < 4; ++dw) {
                    xacc[r][2 * dw]     += __builtin_bit_cast(float, xv[dw] << 16);
                    xacc[r][2 * dw + 1] += __builtin_bit_cast(float, xv[dw] & 0xffff0000u);
                }
#pragma unroll
                for (int j = 0; j < 4; ++j) {
                    float u = a[0] * w0[j] + a[1] * w1[j] + a[2] * w2[j] + a[3] * w3[j] + bb[j];
                    hacc[r][j] += gelu_tanh(u);
                }
            }
        }
    }
#pragma unroll
    for (int r = 0; r < 8; ++r) {
        int rr = r0 + rq * 8 + r;
        short8 xp;
#pragma unroll
        for (int c = 0; c < 8; ++c) xp[c] = f2bs(xacc[r][c]);
        *(short8*)(Xagg + ((size_t)b * N_REC + rr) * 256 + c8) = xp;
        shortx4 hp;
#pragma unroll
        for (int c = 0; c < 4; ++c) hp[c] = f2bs(hacc[r][c]);
        *(shortx4*)(Hagg + (size_t)rr * 256 + hc) = hp;
    }
}

// ==== GEMM kernels: 128x256 block, 4 waves (wave = 64 rows x 128 cols), 32x32x16 MFMA.
// Fragment-major LDS: Al[kgrp][128 rows][8], Bl[kgrp][256 cols][8] -> all ds_read_b128
// lane-consecutive (conflict-free). MFMA operands SWAPPED (A_op=Bfrag, B_op=Afrag) so
// C "col"=lane&31 is the OUTPUT ROW and reg-quads hold 4 consecutive output cols -> packed stores.

// ---- gemm_t: T(98304x256 bf16) = gelu([Xagg|Hagg] @ BT1^T + cnt*cvec + bl1) ----
__global__ __launch_bounds__(256, 2)
void gemm_t(const short* __restrict__ Xagg, const short* __restrict__ Hagg,
            const short* __restrict__ BT1, const float* __restrict__ cvec,
            const float* __restrict__ bl1, const int* __restrict__ bnd,
            short* __restrict__ Tg) {
    __shared__ short Al[8 * 128 * 8];
    __shared__ short Bl[8 * 256 * 8];
    int t = threadIdx.x;
    int lane = t & 63, w = t >> 6;
    int m = lane & 31, q = lane >> 5;
    int R0 = blockIdx.x * 128;
    int rh0 = (R0 < N_REC) ? R0 : R0 - N_REC;
    floatx16 acc[8];
#pragma unroll
    for (int i = 0; i < 8; ++i)
#pragma unroll
        for (int j = 0; j < 16; ++j) acc[i][j] = 0.f;

    int sr = t >> 1;
    int skh = (t & 1) * 4;
    int wr = (w & 1) * 64;
    int wc = (w >> 1) * 128;

    for (int kc = 0; kc < 512; kc += 64) {
        const short* Asrc = (kc < 256)
            ? (Xagg + (size_t)R0 * 256 + kc)
            : (Hagg + (size_t)rh0 * 256 + (kc - 256));
#pragma unroll
        for (int i = 0; i < 4; ++i) {
            short8 v = *(const short8*)(Asrc + sr * 256 + (skh + i) * 8);
            *(short8*)(Al + ((skh + i) * 128 + sr) * 8) = v;
        }
#pragma unroll
        for (int i = 0; i < 8; ++i) {
            short8 v = *(const short8*)(BT1 + (size_t)t * 512 + kc + i * 8);
            *(short8*)(Bl + (i * 256 + t) * 8) = v;
        }
        __syncthreads();
#pragma unroll
        for (int kk = 0; kk < 4; ++kk) {
            int kg = 2 * kk + q;
            short8 a0 = *(const short8*)(Al + (kg * 128 + wr + m) * 8);
            short8 a1 = *(const short8*)(Al + (kg * 128 + wr + 32 + m) * 8);
            short8 b0 = *(const short8*)(Bl + (kg * 256 + wc + m) * 8);
            short8 b1 = *(const short8*)(Bl + (kg * 256 + wc + 32 + m) * 8);
            short8 b2 = *(const short8*)(Bl + (kg * 256 + wc + 64 + m) * 8);
            short8 b3 = *(const short8*)(Bl + (kg * 256 + wc + 96 + m) * 8);
            acc[0] = __builtin_amdgcn_mfma_f32_32x32x16_bf16(b0, a0, acc[0], 0, 0, 0);
            acc[1] = __builtin_amdgcn_mfma_f32_32x32x16_bf16(b1, a0, acc[1], 0, 0, 0);
            acc[2] = __builtin_amdgcn_mfma_f32_32x32x16_bf16(b2, a0, acc[2], 0, 0, 0);
            acc[3] = __builtin_amdgcn_mfma_f32_32x32x16_bf16(b3, a0, acc[3], 0, 0, 0);
            acc[4] = __builtin_amdgcn_mfma_f32_32x32x16_bf16(b0, a1, acc[4], 0, 0, 0);
            acc[5] = __builtin_amdgcn_mfma_f32_32x32x16_bf16(b1, a1, acc[5], 0, 0, 0);
            acc[6] = __builtin_amdgcn_mfma_f32_32x32x16_bf16(b2, a1, acc[6], 0, 0, 0);
            acc[7] = __builtin_amdgcn_mfma_f32_32x32x16_bf16(b3, a1, acc[7], 0, 0, 0);
        }
        __syncthreads();
    }

#pragma unroll
    for (int rt = 0; rt < 2; ++rt) {
        int row = R0 + wr + rt * 32 + m;
        int rmod = (row >= N_REC) ? row - N_REC : row;
        float cnt = (float)(bnd[rmod + 1] - bnd[rmod]);
#pragma unroll
        for (int ct = 0; ct < 4; ++ct) {
#pragma unroll
            for (int qd = 0; qd < 4; ++qd) {
                int c0 = wc + ct * 32 + qd * 8 + q * 4;
                floatx4 cv  = *(const floatx4*)(cvec + c0);
                floatx4 b1v = *(const floatx4*)(bl1 + c0);
                shortx4 pk;
#pragma unroll
                for (int j = 0; j < 4; ++j) {
                    float v = acc[rt * 4 + ct][qd * 4 + j] + cnt * cv[j] + b1v[j];
                    pk[j] = f2bs(gelu_tanh(v));
                }
                *(shortx4*)(Tg + (size_t)row * 256 + c0) = pk;
            }
        }
    }
}

// ---- gemm_o: OUT(98304x256 f32) = T @ WT2^T + bl2 ----
__global__ __launch_bounds__(256, 2)
void gemm_o(const short* __restrict__ Tg, const short* __restrict__ WT2,
            const float* __restrict__ bl2, float* __restrict__ OUT) {
    __shared__ short Al[8 * 128 * 8];
    __shared__ short Bl[8 * 256 * 8];
    int t = threadIdx.x;
    int lane = t & 63, w = t >> 6;
    int m = lane & 31, q = lane >> 5;
    int R0 = blockIdx.x * 128;
    floatx16 acc[8];
#pragma unroll
    for (int i = 0; i < 8; ++i)
#pragma unroll
        for (int j = 0; j < 16; ++j) acc[i][j] = 0.f;

    int sr = t >> 1;
    int skh = (t & 1) * 4;
    int wr = (w & 1) * 64;
    int wc = (w >> 1) * 128;

    for (int kc = 0; kc < 256; kc += 64) {
        const short* Asrc = Tg + (size_t)R0 * 256 + kc;
#pragma unroll
        for (int i = 0; i < 4; ++i) {
            short8 v = *(const short8*)(Asrc + sr * 256 + (skh + i) * 8);
            *(short8*)(Al + ((skh + i) * 128 + sr) * 8) = v;
        }
#pragma unroll
        for (int i = 0; i < 8; ++i) {
            short8 v = *(const short8*)(WT2 + (size_t)t * 256 + kc + i * 8);
            *(short8*)(Bl + (i * 256 + t) * 8) = v;
        }
        __syncthreads();
#pragma unroll
        for (int kk = 0; kk < 4; ++kk) {
            int kg = 2 * kk + q;
            short8 a0 = *(const short8*)(Al + (kg * 128 + wr + m) * 8);
            short8 a1 = *(const short8*)(Al + (kg * 128 + wr + 32 + m) * 8);
            short8 b0 = *(const short8*)(Bl + (kg * 256 + wc + m) * 8);
            short8 b1 = *(const short8*)(Bl + (kg * 256 + wc + 32 + m) * 8);
            short8 b2 = *(const short8*)(Bl + (kg * 256 + wc + 64 + m) * 8);
            short8 b3 = *(const short8*)(Bl + (kg * 256 + wc + 96 + m) * 8);
            acc[0] = __builtin_amdgcn_mfma_f32_32x32x16_bf16(b0, a0, acc[0], 0, 0, 0);
            acc[1] = __builtin_amdgcn_mfma_f32_32x32x16_bf16(b1, a0, acc[1], 0, 0, 0);
            acc[2] = __builtin_amdgcn_mfma_f32_32x32x16_bf16(b2, a0, acc[2], 0, 0, 0);
            acc[3] = __builtin_amdgcn_mfma_f32_32x32x16_bf16(b3, a0, acc[3], 0, 0, 0);
            acc[4] = __builtin_amdgcn_mfma_f32_32x32x16_bf16(b0, a1, acc[4], 0, 0, 0);
            acc[5] = __builtin_amdgcn_mfma_f32_32x32x16_bf16(b1, a1, acc[5], 0, 0, 0);
            acc[6] = __builtin_amdgcn_mfma_f32_32x32x16_bf16(b2, a1, acc[6], 0, 0, 0);
            acc[7] = __builtin_amdgcn_mfma_f32_32x32x16_bf16(b3, a1, acc[7], 0, 0, 0);
        }
        __syncthreads();
    }

#pragma unroll
    for (int rt = 0; rt < 2; ++rt) {
        int row = R0 + wr + rt * 32 + m;
#pragma unroll
        for (int ct = 0; ct < 4; ++ct) {
#pragma unroll
            for (int qd = 0; qd < 4; ++qd) {
                int c0 = wc + ct * 32 + qd * 8 + q * 4;
                floatx4 bv = *(const floatx4*)(bl2 + c0);
                floatx4 o;
#pragma unroll
                for (int j = 0; j < 4; ++j)
                    o[j] = acc[rt * 4 + ct][qd * 4 + j] + bv[j];
                *(floatx4*)(OUT + (size_t)row * 256 + c0) = o;
            }
        }
    }
}

extern "C" void kernel_launch(void* const* d_in, const int* in_sizes, int n_in,
                              void* d_out, int out_size, void* d_ws, size_t ws_size,
                              hipStream_t stream) {
    const float* x        = (const float*)d_in[0];
    const float* ea       = (const float*)d_in[1];
    const int*   idx_send = (const int*)d_in[2];
    const int*   idx_rec  = (const int*)d_in[3];
    const float* We1      = (const float*)d_in[4];
    const float* be1      = (const float*)d_in[5];
    const float* We2      = (const float*)d_in[6];
    const float* be2      = (const float*)d_in[7];
    const float* Wl1      = (const float*)d_in[8];
    const float* bl1      = (const float*)d_in[9];
    const float* Wl2      = (const float*)d_in[10];
    const float* bl2      = (const float*)d_in[11];
    float* out = (float*)d_out;
    char*  ws  = (char*)d_ws;

    short* BT1  = (short*)(ws + 0);           // 262144 B
    short* WT2  = (short*)(ws + 262144);      // 131072 B
    float* cvec = (float*)(ws + 393216);      // 1024 B
    int*   bnd  = (int*)  (ws + 397312);      // 196612 B
    short* Xb   = (short*)(ws + 1048576);     // 12.58 MB
    short* Xagg = (short*)(ws + 16777216);    // 50.33 MB  [2*N_REC][256]
    short* Hagg = (short*)(ws + 67108864);    // 25.17 MB  [N_REC][256]
    short* Tg   = (short*)(ws + 92274688);    // 50.33 MB  [2*N_REC][256]

    prep_kernel<<<257, 256, 0, stream>>>(We2, be2, Wl1, Wl2, BT1, WT2, cvec);
    xcast_kernel<<<(2 * N_SEND * 256) / (256 * 8), 256, 0, stream>>>(x, Xb);
    bounds_kernel<<<(N_REC + 1 + 255) / 256, 256, 0, stream>>>(idx_rec, bnd);
    aggregate<<<N_REC / 32, 256, 0, stream>>>(idx_send, bnd, ea, We1, be1, Xb, Xagg, Hagg);
    gemm_t<<<(2 * N_REC) / 128, 256, 0, stream>>>(Xagg, Hagg, BT1, cvec, bl1, bnd, Tg);
    gemm_o<<<(2 * N_REC) / 128, 256, 0, stream>>>(Tg, WT2, bl2, out);
}

// Round 5
// 287.182 us; speedup vs baseline: 1.1849x; 1.1849x over previous
//
#include <hip/hip_runtime.h>
#include <hip/hip_bf16.h>

#define N_SEND 12288
#define N_REC  49152
#define NEDGE  196608
#define ECAP   512

typedef __attribute__((ext_vector_type(8)))  short short8;
typedef __attribute__((ext_vector_type(4)))  short shortx4;
typedef __attribute__((ext_vector_type(4)))  float floatx4;
typedef __attribute__((ext_vector_type(16))) float floatx16;
typedef __attribute__((ext_vector_type(4)))  unsigned int uintx4;

__device__ inline short f2bs(float f) {
    __hip_bfloat16 h = __float2bfloat16(f);
    return *reinterpret_cast<short*>(&h);
}
// jax.nn.gelu default approximate=True (tanh form)
__device__ inline float gelu_tanh(float x) {
    const float k0 = 0.7978845608028654f;
    float u = k0 * (x + 0.044715f * x * x * x);
    float e = __expf(2.0f * u);
    float t = 1.0f - 2.0f / (e + 1.0f);
    return 0.5f * x * (1.0f + t);
}

// ---- prep: BT1[n][0:256]=Wl1lo^T, BT1[n][256:512]=(We2@Wl1hi)^T, WT2=Wl2^T, cvec=be2@Wl1hi
__global__ void prep_kernel(const float* __restrict__ We2, const float* __restrict__ be2,
                            const float* __restrict__ Wl1, const float* __restrict__ Wl2,
                            short* __restrict__ BT1, short* __restrict__ WT2,
                            float* __restrict__ cvec) {
    int i = blockIdx.x;
    int n = threadIdx.x;
    if (i < 256) {
        float acc = 0.f;
        for (int j = 0; j < 256; ++j)
            acc += We2[i * 256 + j] * Wl1[(256 + j) * 256 + n];
        BT1[n * 512 + i]       = f2bs(Wl1[i * 256 + n]);   // k<256: Wl1lo
        BT1[n * 512 + 256 + i] = f2bs(acc);                // k>=256: M = We2@Wl1hi
        WT2[n * 256 + i]       = f2bs(Wl2[i * 256 + n]);
    } else {
        float acc = 0.f;
        for (int j = 0; j < 256; ++j)
            acc += be2[j] * Wl1[(256 + j) * 256 + n];
        cvec[n] = acc;
    }
}

// ---- xcast: Xb = bf16(X), [2][N_SEND][256]
__global__ void xcast_kernel(const float* __restrict__ X, short* __restrict__ Xb) {
    int i = (blockIdx.x * 256 + threadIdx.x) * 8;
    floatx4 v0 = *(const floatx4*)(X + i);
    floatx4 v1 = *(const floatx4*)(X + i + 4);
    short8 p;
#pragma unroll
    for (int j = 0; j < 4; ++j) { p[j] = f2bs(v0[j]); p[j + 4] = f2bs(v1[j]); }
    *(short8*)(Xb + i) = p;
}

// ---- bounds: bnd[r] = lower_bound(idx_rec, r), r in [0, N_REC]
__global__ void bounds_kernel(const int* __restrict__ idx_rec, int* __restrict__ bnd) {
    int r = blockIdx.x * 256 + threadIdx.x;
    if (r > N_REC) return;
    int lo = 0, hi = NEDGE;
    while (lo < hi) { int mid = (lo + hi) >> 1; if (idx_rec[mid] < r) lo = mid + 1; else hi = mid; }
    bnd[r] = lo;
}

// ==== fused: per block of 64 receivers:
//   phase1: aggregate Xagg(2 batches)/Hagg tiles into LDS (fragment-major)
//   phase2: GEMM1 K=512 ([X|H] @ BT1^T), gelu epilogue -> T back into LDS
//           GEMM2 K=256 (T @ WT2^T) -> OUT
// 512 threads = 8 waves. GEMM wave tile: 128 rows x 32 cols (rows = batch*64+rl).
// Swapped-operand MFMA (verified R4): mfma(colfrag, rowfrag): out-row = lane&31,
// reg quad qd*4+j -> col = wcol + qd*8 + q*4 + j.
__global__ __launch_bounds__(512, 2)
void fused(const int* __restrict__ idx_send, const int* __restrict__ bnd,
           const float* __restrict__ EA, const float* __restrict__ We1,
           const float* __restrict__ be1, const short* __restrict__ Xb,
           const short* __restrict__ BT1, const short* __restrict__ WT2,
           const float* __restrict__ cvec, const float* __restrict__ bl1,
           const float* __restrict__ bl2, float* __restrict__ OUT) {
    __shared__ short XT[32 * 128 * 8];   // [kg][row=b*64+rl][8]  (reused for T after GEMM1)
    __shared__ short HT[32 * 64 * 8];    // [kg][rl][8]
    __shared__ int   sb[65];
    __shared__ int   s_idx[ECAP];
    __shared__ float s_ea[ECAP * 4];

    int t = threadIdx.x;
    int r0 = blockIdx.x * 64;
    if (t < 65) sb[t] = bnd[r0 + t];
    __syncthreads();
    int e0 = sb[0], eN = sb[64];

    // ---------------- phase 1: aggregate ----------------
    {
        int cg = t & 31;          // 8-col group
        int b  = (t >> 5) & 1;    // batch
        int rh = t >> 6;          // receiver octet (wave-uniform!)
        int c8 = cg * 8;
        int hc = c8 + 4 * b;

        floatx4 w0 = *(const floatx4*)(We1 + hc);
        floatx4 w1 = *(const floatx4*)(We1 + 256 + hc);
        floatx4 w2 = *(const floatx4*)(We1 + 512 + hc);
        floatx4 w3 = *(const floatx4*)(We1 + 768 + hc);
        floatx4 bb = *(const floatx4*)(be1 + hc);
        const short* xb_t = Xb + (size_t)b * N_SEND * 256 + c8;

        float xacc[8][8];
        float hacc[8][4];
#pragma unroll
        for (int r = 0; r < 8; ++r) {
#pragma unroll
            for (int c = 0; c < 8; ++c) xacc[r][c] = 0.f;
#pragma unroll
            for (int c = 0; c < 4; ++c) hacc[r][c] = 0.f;
        }

        for (int base = e0; base < eN; base += ECAP) {
            int cnt = min(ECAP, eN - base);
            __syncthreads();
            for (int i = t; i < cnt; i += 512) {
                s_idx[i] = idx_send[base + i];
                *(floatx4*)(s_ea + 4 * i) = *(const floatx4*)(EA + (size_t)(base + i) * 4);
            }
            __syncthreads();
#pragma unroll
            for (int r = 0; r < 8; ++r) {
                int rl = rh * 8 + r;
                int es = max(sb[rl], base);
                int ee = min(sb[rl + 1], base + cnt);
                for (int e = es; e < ee; ++e) {
                    int li = e - base;
                    int s = s_idx[li];
                    uintx4 xv = *(const uintx4*)(xb_t + (size_t)s * 256);
                    floatx4 a = *(const floatx4*)(s_ea + 4 * li);
#pragma unroll
                    for (int dw = 0; dw < 4; ++dw) {
                        xacc[r][2 * dw]     += __builtin_bit_cast(float, xv[dw] << 16);
                        xacc[r][2 * dw + 1] += __builtin_bit_cast(float, xv[dw] & 0xffff0000u);
                    }
#pragma unroll
                    for (int j = 0; j < 4; ++j) {
                        float u = a[0] * w0[j] + a[1] * w1[j] + a[2] * w2[j] + a[3] * w3[j] + bb[j];
                        hacc[r][j] += gelu_tanh(u);
                    }
                }
            }
        }
        // write fragment-major tiles
#pragma unroll
        for (int r = 0; r < 8; ++r) {
            int rl = rh * 8 + r;
            int row = b * 64 + rl;
            short8 xp;
#pragma unroll
            for (int c = 0; c < 8; ++c) xp[c] = f2bs(xacc[r][c]);
            *(short8*)(XT + (cg * 128 + row) * 8) = xp;
            shortx4 hp;
#pragma unroll
            for (int c = 0; c < 4; ++c) hp[c] = f2bs(hacc[r][c]);
            *(shortx4*)(HT + (cg * 64 + rl) * 8 + 4 * b) = hp;
        }
    }
    __syncthreads();

    // ---------------- phase 2: GEMM1 (K=512) ----------------
    int w = t >> 6, lane = t & 63;
    int m = lane & 31, q = lane >> 5;
    int wcol = w * 32;
    floatx16 acc[4];
#pragma unroll
    for (int i = 0; i < 4; ++i)
#pragma unroll
        for (int j = 0; j < 16; ++j) acc[i][j] = 0.f;

    const short* Bp1 = BT1 + (size_t)(wcol + m) * 512 + q * 8;
    short8 bfA[4], bfB[4];
#pragma unroll
    for (int kk = 0; kk < 4; ++kk) bfA[kk] = *(const short8*)(Bp1 + kk * 16);

#pragma unroll
    for (int ci = 0; ci < 8; ++ci) {
        int kc = ci * 64;
        const short8* bc = (ci & 1) ? bfB : bfA;
        short8*       bn = (ci & 1) ? bfA : bfB;
        if (ci < 7) {
#pragma unroll
            for (int kk = 0; kk < 4; ++kk)
                bn[kk] = *(const short8*)(Bp1 + kc + 64 + kk * 16);
        }
#pragma unroll
        for (int kk = 0; kk < 4; ++kk) {
            int f = (kc >> 3) + 2 * kk + q;
#pragma unroll
            for (int rt = 0; rt < 4; ++rt) {
                int row = rt * 32 + m;
                const short* ap = (ci < 4)
                    ? (XT + (f * 128 + row) * 8)
                    : (HT + ((f - 32) * 64 + (row & 63)) * 8);
                short8 a = *(const short8*)ap;
                acc[rt] = __builtin_amdgcn_mfma_f32_32x32x16_bf16(bc[kk], a, acc[rt], 0, 0, 0);
            }
        }
    }
    __syncthreads();   // all waves done reading XT/HT

    // ---- epilogue1: gelu(acc + cnt*cvec + bl1) -> T (into XT, fragment-major) ----
#pragma unroll
    for (int rt = 0; rt < 4; ++rt) {
        int row = rt * 32 + m;
        int rl = row & 63;
        float cntv = (float)(sb[rl + 1] - sb[rl]);
#pragma unroll
        for (int qd = 0; qd < 4; ++qd) {
            int c0 = wcol + qd * 8 + q * 4;
            floatx4 cv  = *(const floatx4*)(cvec + c0);
            floatx4 b1v = *(const floatx4*)(bl1 + c0);
            shortx4 pk;
#pragma unroll
            for (int j = 0; j < 4; ++j)
                pk[j] = f2bs(gelu_tanh(acc[rt][qd * 4 + j] + cntv * cv[j] + b1v[j]));
            *(shortx4*)(XT + ((w * 4 + qd) * 128 + row) * 8 + q * 4) = pk;
        }
#pragma unroll
        for (int j = 0; j < 16; ++j) acc[rt][j] = 0.f;
    }
    __syncthreads();

    // ---------------- GEMM2 (K=256): T @ WT2^T ----------------
    const short* Bp2 = WT2 + (size_t)(wcol + m) * 256 + q * 8;
#pragma unroll
    for (int kk = 0; kk < 4; ++kk) bfA[kk] = *(const short8*)(Bp2 + kk * 16);

#pragma unroll
    for (int ci = 0; ci < 4; ++ci) {
        int kc = ci * 64;
        const short8* bc = (ci & 1) ? bfB : bfA;
        short8*       bn = (ci & 1) ? bfA : bfB;
        if (ci < 3) {
#pragma unroll
            for (int kk = 0; kk < 4; ++kk)
                bn[kk] = *(const short8*)(Bp2 + kc + 64 + kk * 16);
        }
#pragma unroll
        for (int kk = 0; kk < 4; ++kk) {
            int f2 = (kc >> 3) + 2 * kk + q;
#pragma unroll
            for (int rt = 0; rt < 4; ++rt) {
                short8 a = *(const short8*)(XT + (f2 * 128 + rt * 32 + m) * 8);
                acc[rt] = __builtin_amdgcn_mfma_f32_32x32x16_bf16(bc[kk], a, acc[rt], 0, 0, 0);
            }
        }
    }

    // ---- epilogue2: + bl2 -> OUT ----
#pragma unroll
    for (int rt = 0; rt < 4; ++rt) {
        int row = rt * 32 + m;
        int batch = row >> 6;
        int rl = row & 63;
        size_t obase = ((size_t)batch * N_REC + r0 + rl) * 256;
#pragma unroll
        for (int qd = 0; qd < 4; ++qd) {
            int c0 = wcol + qd * 8 + q * 4;
            floatx4 bv = *(const floatx4*)(bl2 + c0);
            floatx4 o;
#pragma unroll
            for (int j = 0; j < 4; ++j)
                o[j] = acc[rt][qd * 4 + j] + bv[j];
            *(floatx4*)(OUT + obase + c0) = o;
        }
    }
}

extern "C" void kernel_launch(void* const* d_in, const int* in_sizes, int n_in,
                              void* d_out, int out_size, void* d_ws, size_t ws_size,
                              hipStream_t stream) {
    const float* x        = (const float*)d_in[0];
    const float* ea       = (const float*)d_in[1];
    const int*   idx_send = (const int*)d_in[2];
    const int*   idx_rec  = (const int*)d_in[3];
    const float* We1      = (const float*)d_in[4];
    const float* be1      = (const float*)d_in[5];
    const float* We2      = (const float*)d_in[6];
    const float* be2      = (const float*)d_in[7];
    const float* Wl1      = (const float*)d_in[8];
    const float* bl1      = (const float*)d_in[9];
    const float* Wl2      = (const float*)d_in[10];
    const float* bl2      = (const float*)d_in[11];
    float* out = (float*)d_out;
    char*  ws  = (char*)d_ws;

    short* BT1  = (short*)(ws + 0);           // 262144 B
    short* WT2  = (short*)(ws + 262144);      // 131072 B
    float* cvec = (float*)(ws + 393216);      // 1024 B
    int*   bnd  = (int*)  (ws + 397312);      // 196612 B
    short* Xb   = (short*)(ws + 1048576);     // 12.58 MB

    prep_kernel<<<257, 256, 0, stream>>>(We2, be2, Wl1, Wl2, BT1, WT2, cvec);
    xcast_kernel<<<(2 * N_SEND * 256) / (256 * 8), 256, 0, stream>>>(x, Xb);
    bounds_kernel<<<(N_REC + 1 + 255) / 256, 256, 0, stream>>>(idx_rec, bnd);
    fused<<<N_REC / 64, 512, 0, stream>>>(idx_send, bnd, ea, We1, be1, Xb,
                                          BT1, WT2, cvec, bl1, bl2, out);
}